// Round 14
// baseline (201.445 us; speedup 1.0000x reference)
//
#include <hip/hip_runtime.h>
#include <math.h>

// FilterMLPBlock: out = LN_D( irfft(rfft(x,ortho)*w,ortho) + x ),  B=4096,S=64,D=256
// R14 = R11 (130.0us, best) + occupancy push: 5 blocks/CU (62%).
//   h = C2 * ((W+1) o (C1 * x))        [residual folded: C2*C1 = I]
//   GEMM1/GEMM2: K=64 plain-bf16, v_cvt_pk_bf16_f32 packing.
// R13 post-mortem: float4 x-restructure spilled (xq[32] + acc[64] > 128-reg
// unified cap at (256,4)): WRITE 262->351MB. Reverted to R11's per-kt scalar
// loads (~95-100 peak regs).
// R14 changes (minimal, occupancy only):
//  - VROW 144->128 + XOR swizzle (byte ^= (dl&7)<<4, SAME on write & read):
//    V region exactly 32 KB for 4 waves.
//  - LN partials as cvtpk-packed (bf16,bf16) u32 [64][68] (R10 precedent) +
//    2-stage combine + mr, ALL overlaid inside the 32 KB (V dead by then).
//    Block LDS = 32768 exactly -> 5 blocks/CU (160KB/32KB; granted exact).
//  - launch_bounds(256,5): unified cap 102 vs ~95-100 demand.
// Tripwire: WRITE_SIZE > 262 MB => register budget didn't fit (spill) =>
// revert arg2 to 4 next round.

typedef __attribute__((ext_vector_type(8))) short short8;
typedef __attribute__((ext_vector_type(4))) float f32x4;
typedef __attribute__((ext_vector_type(4))) unsigned int u32x4;
typedef __attribute__((ext_vector_type(2))) unsigned int u32x2;

#define VROW 128   // V row stride bytes (64 bf16); bank spread via XOR swizzle

__device__ __forceinline__ unsigned short bf16rn(float v) {
    unsigned u = __float_as_uint(v);
    u += 0x7fffu + ((u >> 16) & 1u);
    return (unsigned short)(u >> 16);
}
__device__ __forceinline__ float bf16tof(unsigned short h) {
    return __uint_as_float(((unsigned)h) << 16);
}
// hardware packed convert: dst = (bf16(a) in lo16, bf16(b) in hi16), RNE
__device__ __forceinline__ unsigned cvtpk(float a, float b) {
    unsigned r;
    asm("v_cvt_pk_bf16_f32 %0, %1, %2" : "=v"(r) : "v"(a), "v"(b));
    return r;
}

// A tables in ws: A1 = 8 frags (K=64, C1), 8 KB; A2 = 8 frags (K=64, C2),
// 8 KB at short-offset 4096. Frag layout (HW-verified R8-R13 passing):
// lane l, j=0..7: m = mi*16 + (l&15), k = kt*32 + 8*(l>>4) + j.
__global__ void pack_A_kernel(unsigned short* __restrict__ apack) {
    const int bid  = blockIdx.x;         // 0..15
    const int lane = threadIdx.x;        // 0..63
    const float step = 6.28318530717958647692f / 64.f;
    const int fid = bid & 7;
    const int kt = fid >> 2, mi = fid & 3;
    const int m = mi * 16 + (lane & 15);
    if (bid < 8) {                       // A1 = C1 (rfft, ortho, re||im rows)
        unsigned short* dst = apack + ((size_t)fid * 64 + lane) * 8;
        #pragma unroll
        for (int j = 0; j < 8; ++j) {
            const int t = kt * 32 + 8 * (lane >> 4) + j;    // time index
            float val;
            if (m <= 32) val =  cosf(step * (float)((m * t) & 63)) * 0.125f;
            else         val = -sinf(step * (float)(((m - 32) * t) & 63)) * 0.125f;
            dst[j] = bf16rn(val);
        }
    } else {                             // A2 = C2 (irfft, ortho)
        unsigned short* dst = apack + 4096 + ((size_t)fid * 64 + lane) * 8;
        #pragma unroll
        for (int j = 0; j < 8; ++j) {
            const int c = kt * 32 + 8 * (lane >> 4) + j;    // V-row index
            float val;
            if (c == 0)       val = 0.125f;
            else if (c == 32) val = (m & 1) ? -0.125f : 0.125f;
            else if (c < 32)  val =  0.25f * cosf(step * (float)((c * m) & 63));
            else              val = -0.25f * sinf(step * (float)(((c - 32) * m) & 63));
            dst[j] = bf16rn(val);
        }
    }
}

#define MFMA(A, B, C) __builtin_amdgcn_mfma_f32_16x16x32_bf16( \
    __builtin_bit_cast(short8, A), (B), (C), 0, 0, 0)

__global__ __launch_bounds__(256, 5)
void fft_ln_kernel(const float* __restrict__ x,
                   const float* __restrict__ cw,
                   const float* __restrict__ gamma,
                   const float* __restrict__ beta,
                   const unsigned short* __restrict__ apack,
                   float* __restrict__ out) {
    __shared__ __align__(16) char smem[32768];   // V (32KB); LN overlays after
    const int tid = threadIdx.x, lane = tid & 63, wv = tid >> 6;
    const int hi = lane >> 4, lm = lane & 15;
    const int b = blockIdx.x, dbase = wv * 64;
    const float* __restrict__ xb = x + (size_t)b * 16384;
    const u32x4* __restrict__ ap1 = (const u32x4*)apack;
    const u32x4* __restrict__ ap2 = (const u32x4*)(apack + 4096);

    f32x4 acc[16];                       // [mi*4+ni]
    #pragma unroll
    for (int i = 0; i < 16; ++i) acc[i] = (f32x4)0.f;

    // ---- GEMM1: U = C1*x, K=64 plain bf16. x packed by v_cvt_pk (RNE). ----
    #pragma unroll
    for (int kt = 0; kt < 2; ++kt) {
        const u32x4 af0 = ap1[(kt * 4 + 0) * 64 + lane];
        const u32x4 af1 = ap1[(kt * 4 + 1) * 64 + lane];
        const u32x4 af2 = ap1[(kt * 4 + 2) * 64 + lane];
        const u32x4 af3 = ap1[(kt * 4 + 3) * 64 + lane];
        const float* __restrict__ xp = xb + (kt * 32 + 8 * hi) * 256 + dbase + lm;
        #pragma unroll
        for (int ni = 0; ni < 4; ++ni) {
            float xv[8];
            #pragma unroll
            for (int j = 0; j < 8; ++j) xv[j] = xp[j * 256 + ni * 16];
            u32x4 bw;
            bw[0] = cvtpk(xv[0], xv[1]);
            bw[1] = cvtpk(xv[2], xv[3]);
            bw[2] = cvtpk(xv[4], xv[5]);
            bw[3] = cvtpk(xv[6], xv[7]);
            const short8 bb = __builtin_bit_cast(short8, bw);
            acc[0 * 4 + ni] = MFMA(af0, bb, acc[0 * 4 + ni]);
            acc[1 * 4 + ni] = MFMA(af1, bb, acc[1 * 4 + ni]);
            acc[2 * 4 + ni] = MFMA(af2, bb, acc[2 * 4 + ni]);
            acc[3 * 4 + ni] = MFMA(af3, bb, acc[3 * 4 + ni]);
        }
    }

    // ---- filter multiply with residual fold: V = (W+1) o U (fp32, lane-local)
    #pragma unroll
    for (int mi = 0; mi < 2; ++mi)
    #pragma unroll
    for (int ni = 0; ni < 4; ++ni) {
        const int d = dbase + ni * 16 + lm;
        #pragma unroll
        for (int r = 0; r < 4; ++r) {
            const int f = mi * 16 + hi * 4 + r;
            const float2 wc = *(const float2*)(cw + ((size_t)(f * 256 + d)) * 2);
            const float wr1 = wc.x + 1.f;
            const float Ure = acc[mi * 4 + ni][r];
            const float Uim = acc[(mi + 2) * 4 + ni][r];
            float Vre = Ure * wr1 - Uim * wc.y;
            float Vim = Ure * wc.y + Uim * wr1;
            if (mi == 0 && r == 0) {                 // f==0 lanes: DC & Nyquist
                const float w32 = cw[(32 * 256 + d) * 2] + 1.f;
                if (hi == 0) { Vre = Ure * wr1; Vim = Uim * w32; }
            }
            acc[mi * 4 + ni][r]       = Vre;
            acc[(mi + 2) * 4 + ni][r] = Vim;
        }
    }

    // ---- V -> bf16 LDS [dl][f] via cvt_pk; wave-private 8 KB; XOR swizzle ----
    char* vb = smem + wv * 64 * VROW;
    #pragma unroll
    for (int mi = 0; mi < 4; ++mi)
    #pragma unroll
    for (int ni = 0; ni < 4; ++ni) {
        const f32x4 a4 = acc[mi * 4 + ni];
        u32x2 p;
        p[0] = cvtpk(a4[0], a4[1]);
        p[1] = cvtpk(a4[2], a4[3]);
        const int dl = ni * 16 + lm;
        unsigned off = (unsigned)(dl * VROW + mi * 32 + hi * 8);
        off ^= (unsigned)((dl & 7) << 4);            // bank swizzle (write side)
        *(u32x2*)(vb + off) = p;                      // f0 = mi*16+hi*4
    }

    // ---- GEMM2: h = C2 * V, K=64 plain bf16 (acc regs reused, re-zeroed) ----
    #pragma unroll
    for (int i = 0; i < 16; ++i) acc[i] = (f32x4)0.f;
    #pragma unroll
    for (int kt = 0; kt < 2; ++kt) {
        const u32x4 af0 = ap2[(kt * 4 + 0) * 64 + lane];
        const u32x4 af1 = ap2[(kt * 4 + 1) * 64 + lane];
        const u32x4 af2 = ap2[(kt * 4 + 2) * 64 + lane];
        const u32x4 af3 = ap2[(kt * 4 + 3) * 64 + lane];
        #pragma unroll
        for (int ni = 0; ni < 4; ++ni) {
            const int dl = ni * 16 + lm;
            unsigned off = (unsigned)(dl * VROW + kt * 64 + hi * 16);
            off ^= (unsigned)((dl & 7) << 4);        // same swizzle (read side)
            const u32x4 bw = *(const u32x4*)(vb + off);
            const short8 bb = __builtin_bit_cast(short8, bw);
            acc[0 * 4 + ni] = MFMA(af0, bb, acc[0 * 4 + ni]);
            acc[1 * 4 + ni] = MFMA(af1, bb, acc[1 * 4 + ni]);
            acc[2 * 4 + ni] = MFMA(af2, bb, acc[2 * 4 + ni]);
            acc[3 * 4 + ni] = MFMA(af3, bb, acc[3 * 4 + ni]);
        }
    }

    // ---- LayerNorm over d: packed (bf16,bf16) partials overlay V region ----
    __syncthreads();                       // all waves done reading their V
    unsigned* pp = (unsigned*)smem;        // [64][68] u32, 17408 B
    float* ps2 = (float*)(smem + 17408);   // [64][5], 1280 B
    float* pq2 = (float*)(smem + 18688);   // [64][5], 1280 B
    float* mr  = (float*)(smem + 19968);   // [64][2] mean, rstd (512 B) <=32768
    #pragma unroll
    for (int mi = 0; mi < 4; ++mi)
    #pragma unroll
    for (int r = 0; r < 4; ++r) {
        float s1 = 0.f, s2 = 0.f;
        #pragma unroll
        for (int ni = 0; ni < 4; ++ni) {
            const float v = acc[mi * 4 + ni][r];
            s1 += v;
            s2 = fmaf(v, v, s2);
        }
        const int row = mi * 16 + hi * 4 + r;
        pp[row * 68 + wv * 16 + lm] = cvtpk(s1, s2);
    }
    __syncthreads();
    {   // parallel combine: thread (row = tid&63, g = wv) sums 16 cols
        const int row = tid & 63;
        float s1 = 0.f, s2 = 0.f;
        #pragma unroll
        for (int j = 0; j < 16; ++j) {
            const unsigned v = pp[row * 68 + wv * 16 + j];
            s1 += bf16tof((unsigned short)(v & 0xffffu));
            s2 += bf16tof((unsigned short)(v >> 16));
        }
        ps2[row * 5 + wv] = s1;
        pq2[row * 5 + wv] = s2;
    }
    __syncthreads();
    if (tid < 64) {
        const float s1 = ps2[tid * 5] + ps2[tid * 5 + 1] + ps2[tid * 5 + 2] + ps2[tid * 5 + 3];
        const float s2 = pq2[tid * 5] + pq2[tid * 5 + 1] + pq2[tid * 5 + 2] + pq2[tid * 5 + 3];
        const float mean = s1 * (1.f / 256.f);
        const float var  = s2 * (1.f / 256.f) - mean * mean;
        mr[tid * 2 + 0] = mean;
        mr[tid * 2 + 1] = rsqrtf(var + 1e-12f);
    }
    __syncthreads();

    // ---- normalize + affine + store (64B segments per 16-lane group) ----
    f32x4 gv, bv;
    #pragma unroll
    for (int ni = 0; ni < 4; ++ni) {
        gv[ni] = gamma[dbase + ni * 16 + lm];
        bv[ni] = beta [dbase + ni * 16 + lm];
    }
    float* __restrict__ ob = out + (size_t)b * 16384;
    #pragma unroll
    for (int mi = 0; mi < 4; ++mi)
    #pragma unroll
    for (int r = 0; r < 4; ++r) {
        const int row = mi * 16 + hi * 4 + r;
        const float m  = mr[row * 2 + 0];
        const float rs = mr[row * 2 + 1];
        #pragma unroll
        for (int ni = 0; ni < 4; ++ni)
            ob[row * 256 + dbase + ni * 16 + lm] =
                (acc[mi * 4 + ni][r] - m) * rs * gv[ni] + bv[ni];
    }
}

extern "C" void kernel_launch(void* const* d_in, const int* in_sizes, int n_in,
                              void* d_out, int out_size, void* d_ws, size_t ws_size,
                              hipStream_t stream) {
    const float* x     = (const float*)d_in[0];
    const float* cw    = (const float*)d_in[1];   // [1,33,256,2]
    const float* gamma = (const float*)d_in[2];
    const float* beta  = (const float*)d_in[3];
    float* outp = (float*)d_out;
    unsigned short* apack = (unsigned short*)d_ws;   // 16 KB fragment tables

    pack_A_kernel<<<16, 64, 0, stream>>>(apack);
    fft_ln_kernel<<<4096, 256, 0, stream>>>(x, cw, gamma, beta, apack, outp);
}

// Round 15
// 135.427 us; speedup vs baseline: 1.4875x; 1.4875x over previous
//
#include <hip/hip_runtime.h>
#include <math.h>

// FilterMLPBlock: out = LN_D( irfft(rfft(x,ortho)*w,ortho) + x ),  B=4096,S=64,D=256
// R15 = R11 (130.0us, best) + register-safe float4 loads + swizzled 32KB LDS.
//   h = C2 * ((W+1) o (C1 * x))        [residual folded: C2*C1 = I]
//   GEMM1/GEMM2: K=64 plain-bf16, v_cvt_pk_bf16_f32 packing.
// R14 post-mortem: (256,5) cap 102 < ~128 demand -> spill (WRITE 444MB).
//   4 waves/EU is the max for this structure; back to (256,4).
// Salvaged, correctness-verified pieces:
//  - R13's GEMM1 d-permutation (col lm of frag ni = d dbase+4lm+ni): x as 16
//    coalesced dwordx4 (was 64 scalars), cw as float4 pairs. R13's spill is
//    avoided by consuming each float4 pair immediately (peak live ~114 < 128).
//  - R14's VROW=128 XOR swizzle (write+read same involution; conflicts 1.0M)
//    and packed-bf16 LN partials: block LDS = 32768 B.
// GEMM2 re-establishes the old column mapping (dl = ni*16+lm), so the filter
// -> V-write handles the permutation and LN/store are untouched R11 code.
// Tripwire: WRITE_SIZE > 262 MB => hoisting spilled => revert to R11 verbatim.

typedef __attribute__((ext_vector_type(8))) short short8;
typedef __attribute__((ext_vector_type(4))) float f32x4;
typedef __attribute__((ext_vector_type(4))) unsigned int u32x4;
typedef __attribute__((ext_vector_type(2))) unsigned int u32x2;

#define VROW 128   // V row stride bytes (64 bf16); bank spread via XOR swizzle

__device__ __forceinline__ unsigned short bf16rn(float v) {
    unsigned u = __float_as_uint(v);
    u += 0x7fffu + ((u >> 16) & 1u);
    return (unsigned short)(u >> 16);
}
__device__ __forceinline__ float bf16tof(unsigned short h) {
    return __uint_as_float(((unsigned)h) << 16);
}
// hardware packed convert: dst = (bf16(a) in lo16, bf16(b) in hi16), RNE
__device__ __forceinline__ unsigned cvtpk(float a, float b) {
    unsigned r;
    asm("v_cvt_pk_bf16_f32 %0, %1, %2" : "=v"(r) : "v"(a), "v"(b));
    return r;
}

// A tables in ws: A1 = 8 frags (K=64, C1), 8 KB; A2 = 8 frags (K=64, C2),
// 8 KB at short-offset 4096. Frag layout (HW-verified R8-R14 passing):
// lane l, j=0..7: m = mi*16 + (l&15), k = kt*32 + 8*(l>>4) + j.
__global__ void pack_A_kernel(unsigned short* __restrict__ apack) {
    const int bid  = blockIdx.x;         // 0..15
    const int lane = threadIdx.x;        // 0..63
    const float step = 6.28318530717958647692f / 64.f;
    const int fid = bid & 7;
    const int kt = fid >> 2, mi = fid & 3;
    const int m = mi * 16 + (lane & 15);
    if (bid < 8) {                       // A1 = C1 (rfft, ortho, re||im rows)
        unsigned short* dst = apack + ((size_t)fid * 64 + lane) * 8;
        #pragma unroll
        for (int j = 0; j < 8; ++j) {
            const int t = kt * 32 + 8 * (lane >> 4) + j;    // time index
            float val;
            if (m <= 32) val =  cosf(step * (float)((m * t) & 63)) * 0.125f;
            else         val = -sinf(step * (float)(((m - 32) * t) & 63)) * 0.125f;
            dst[j] = bf16rn(val);
        }
    } else {                             // A2 = C2 (irfft, ortho)
        unsigned short* dst = apack + 4096 + ((size_t)fid * 64 + lane) * 8;
        #pragma unroll
        for (int j = 0; j < 8; ++j) {
            const int c = kt * 32 + 8 * (lane >> 4) + j;    // V-row index
            float val;
            if (c == 0)       val = 0.125f;
            else if (c == 32) val = (m & 1) ? -0.125f : 0.125f;
            else if (c < 32)  val =  0.25f * cosf(step * (float)((c * m) & 63));
            else              val = -0.25f * sinf(step * (float)(((c - 32) * m) & 63));
            dst[j] = bf16rn(val);
        }
    }
}

#define MFMA(A, B, C) __builtin_amdgcn_mfma_f32_16x16x32_bf16( \
    __builtin_bit_cast(short8, A), (B), (C), 0, 0, 0)

__global__ __launch_bounds__(256, 4)
void fft_ln_kernel(const float* __restrict__ x,
                   const float* __restrict__ cw,
                   const float* __restrict__ gamma,
                   const float* __restrict__ beta,
                   const unsigned short* __restrict__ apack,
                   float* __restrict__ out) {
    __shared__ __align__(16) char smem[32768];   // V (32KB); LN overlays after
    const int tid = threadIdx.x, lane = tid & 63, wv = tid >> 6;
    const int hi = lane >> 4, lm = lane & 15;
    const int b = blockIdx.x, dbase = wv * 64;
    const float* __restrict__ xb = x + (size_t)b * 16384;
    const u32x4* __restrict__ ap1 = (const u32x4*)apack;
    const u32x4* __restrict__ ap2 = (const u32x4*)(apack + 4096);

    f32x4 acc[16];                       // [mi*4+ni]; GEMM1: col lm of frag ni
    #pragma unroll                       //  holds physical d = dbase + 4*lm + ni
    for (int i = 0; i < 16; ++i) acc[i] = (f32x4)0.f;

    // ---- GEMM1: U = C1*x, K=64 bf16; x via dwordx4, consumed immediately ----
    #pragma unroll
    for (int kt = 0; kt < 2; ++kt) {
        const u32x4 af0 = ap1[(kt * 4 + 0) * 64 + lane];
        const u32x4 af1 = ap1[(kt * 4 + 1) * 64 + lane];
        const u32x4 af2 = ap1[(kt * 4 + 2) * 64 + lane];
        const u32x4 af3 = ap1[(kt * 4 + 3) * 64 + lane];
        const float* __restrict__ xp = xb + (kt * 32 + 8 * hi) * 256 + dbase + 4 * lm;
        u32x4 bw0, bw1, bw2, bw3;        // B-frags for ni = 0..3 (16 regs)
        #pragma unroll
        for (int jp = 0; jp < 4; ++jp) { // pair of time steps; pair regs die fast
            const f32x4 xa = *(const f32x4*)(xp + (2 * jp + 0) * 256);
            const f32x4 xc = *(const f32x4*)(xp + (2 * jp + 1) * 256);
            bw0[jp] = cvtpk(xa[0], xc[0]);
            bw1[jp] = cvtpk(xa[1], xc[1]);
            bw2[jp] = cvtpk(xa[2], xc[2]);
            bw3[jp] = cvtpk(xa[3], xc[3]);
        }
        acc[0]  = MFMA(af0, __builtin_bit_cast(short8, bw0), acc[0]);
        acc[4]  = MFMA(af1, __builtin_bit_cast(short8, bw0), acc[4]);
        acc[8]  = MFMA(af2, __builtin_bit_cast(short8, bw0), acc[8]);
        acc[12] = MFMA(af3, __builtin_bit_cast(short8, bw0), acc[12]);
        acc[1]  = MFMA(af0, __builtin_bit_cast(short8, bw1), acc[1]);
        acc[5]  = MFMA(af1, __builtin_bit_cast(short8, bw1), acc[5]);
        acc[9]  = MFMA(af2, __builtin_bit_cast(short8, bw1), acc[9]);
        acc[13] = MFMA(af3, __builtin_bit_cast(short8, bw1), acc[13]);
        acc[2]  = MFMA(af0, __builtin_bit_cast(short8, bw2), acc[2]);
        acc[6]  = MFMA(af1, __builtin_bit_cast(short8, bw2), acc[6]);
        acc[10] = MFMA(af2, __builtin_bit_cast(short8, bw2), acc[10]);
        acc[14] = MFMA(af3, __builtin_bit_cast(short8, bw2), acc[14]);
        acc[3]  = MFMA(af0, __builtin_bit_cast(short8, bw3), acc[3]);
        acc[7]  = MFMA(af1, __builtin_bit_cast(short8, bw3), acc[7]);
        acc[11] = MFMA(af2, __builtin_bit_cast(short8, bw3), acc[11]);
        acc[15] = MFMA(af3, __builtin_bit_cast(short8, bw3), acc[15]);
    }

    // ---- filter multiply + residual fold: V = (W+1) o U (fp32, lane-local)
    // cw for this thread's 4 d's = 8 consecutive floats -> 2x float4 per f.
    const float* __restrict__ cwb = cw + 2 * (size_t)(dbase + 4 * lm);
    f32x4 nqa = *(const f32x4*)(cwb + 2 * 32 * 256);      // Nyquist (re,im)x2
    f32x4 nqb = *(const f32x4*)(cwb + 2 * 32 * 256 + 4);
    float w32r[4] = {nqa[0], nqa[2], nqb[0], nqb[2]};
    #pragma unroll
    for (int mi = 0; mi < 2; ++mi)
    #pragma unroll
    for (int r = 0; r < 4; ++r) {
        const int f = mi * 16 + hi * 4 + r;
        const f32x4 ca = *(const f32x4*)(cwb + 2 * (size_t)f * 256);
        const f32x4 cb = *(const f32x4*)(cwb + 2 * (size_t)f * 256 + 4);
        #pragma unroll
        for (int ni = 0; ni < 4; ++ni) {
            const float wre = (ni == 0) ? ca[0] : (ni == 1) ? ca[2]
                            : (ni == 2) ? cb[0] : cb[2];
            const float wim = (ni == 0) ? ca[1] : (ni == 1) ? ca[3]
                            : (ni == 2) ? cb[1] : cb[3];
            const float wr1 = wre + 1.f;
            const float Ure = acc[mi * 4 + ni][r];
            const float Uim = acc[(mi + 2) * 4 + ni][r];
            float Vre = Ure * wr1 - Uim * wim;
            float Vim = Ure * wim + Uim * wr1;
            if (mi == 0 && r == 0) {                 // f==0 lanes: DC & Nyquist
                if (hi == 0) { Vre = Ure * wr1; Vim = Uim * (w32r[ni] + 1.f); }
            }
            acc[mi * 4 + ni][r]       = Vre;
            acc[(mi + 2) * 4 + ni][r] = Vim;
        }
    }

    // ---- V -> bf16 LDS; physical rows dl = 4*lm + ni; XOR swizzle ----
    char* vb = smem + wv * 64 * VROW;
    #pragma unroll
    for (int mi = 0; mi < 4; ++mi)
    #pragma unroll
    for (int ni = 0; ni < 4; ++ni) {
        const f32x4 a4 = acc[mi * 4 + ni];
        u32x2 p;
        p[0] = cvtpk(a4[0], a4[1]);
        p[1] = cvtpk(a4[2], a4[3]);
        const int dl = 4 * lm + ni;
        unsigned off = (unsigned)(dl * VROW + mi * 32 + hi * 8);
        off ^= (unsigned)((dl & 7) << 4);            // swizzle (write side)
        *(u32x2*)(vb + off) = p;                      // f0 = mi*16+hi*4
    }

    // ---- GEMM2: h = C2 * V, K=64 bf16; old mapping dl = ni*16+lm ----
    #pragma unroll
    for (int i = 0; i < 16; ++i) acc[i] = (f32x4)0.f;
    #pragma unroll
    for (int kt = 0; kt < 2; ++kt) {
        const u32x4 af0 = ap2[(kt * 4 + 0) * 64 + lane];
        const u32x4 af1 = ap2[(kt * 4 + 1) * 64 + lane];
        const u32x4 af2 = ap2[(kt * 4 + 2) * 64 + lane];
        const u32x4 af3 = ap2[(kt * 4 + 3) * 64 + lane];
        #pragma unroll
        for (int ni = 0; ni < 4; ++ni) {
            const int dl = ni * 16 + lm;
            unsigned off = (unsigned)(dl * VROW + kt * 64 + hi * 16);
            off ^= (unsigned)((dl & 7) << 4);        // same swizzle (read side)
            const u32x4 bw = *(const u32x4*)(vb + off);
            const short8 bb = __builtin_bit_cast(short8, bw);
            acc[0 * 4 + ni] = MFMA(af0, bb, acc[0 * 4 + ni]);
            acc[1 * 4 + ni] = MFMA(af1, bb, acc[1 * 4 + ni]);
            acc[2 * 4 + ni] = MFMA(af2, bb, acc[2 * 4 + ni]);
            acc[3 * 4 + ni] = MFMA(af3, bb, acc[3 * 4 + ni]);
        }
    }

    // ---- LayerNorm over d: packed (bf16,bf16) partials overlay V region ----
    __syncthreads();                       // all waves done reading their V
    unsigned* pp = (unsigned*)smem;        // [64][68] u32, 17408 B
    float* ps2 = (float*)(smem + 17408);   // [64][5], 1280 B
    float* pq2 = (float*)(smem + 18688);   // [64][5], 1280 B
    float* mr  = (float*)(smem + 19968);   // [64][2] mean, rstd (512 B) <=32768
    #pragma unroll
    for (int mi = 0; mi < 4; ++mi)
    #pragma unroll
    for (int r = 0; r < 4; ++r) {
        float s1 = 0.f, s2 = 0.f;
        #pragma unroll
        for (int ni = 0; ni < 4; ++ni) {
            const float v = acc[mi * 4 + ni][r];
            s1 += v;
            s2 = fmaf(v, v, s2);
        }
        const int row = mi * 16 + hi * 4 + r;
        pp[row * 68 + wv * 16 + lm] = cvtpk(s1, s2);
    }
    __syncthreads();
    {   // parallel combine: thread (row = tid&63, g = wv) sums 16 cols
        const int row = tid & 63;
        float s1 = 0.f, s2 = 0.f;
        #pragma unroll
        for (int j = 0; j < 16; ++j) {
            const unsigned v = pp[row * 68 + wv * 16 + j];
            s1 += bf16tof((unsigned short)(v & 0xffffu));
            s2 += bf16tof((unsigned short)(v >> 16));
        }
        ps2[row * 5 + wv] = s1;
        pq2[row * 5 + wv] = s2;
    }
    __syncthreads();
    if (tid < 64) {
        const float s1 = ps2[tid * 5] + ps2[tid * 5 + 1] + ps2[tid * 5 + 2] + ps2[tid * 5 + 3];
        const float s2 = pq2[tid * 5] + pq2[tid * 5 + 1] + pq2[tid * 5 + 2] + pq2[tid * 5 + 3];
        const float mean = s1 * (1.f / 256.f);
        const float var  = s2 * (1.f / 256.f) - mean * mean;
        mr[tid * 2 + 0] = mean;
        mr[tid * 2 + 1] = rsqrtf(var + 1e-12f);
    }
    __syncthreads();

    // ---- normalize + affine + store (64B segments per 16-lane group) ----
    f32x4 gv, bv;
    #pragma unroll
    for (int ni = 0; ni < 4; ++ni) {
        gv[ni] = gamma[dbase + ni * 16 + lm];
        bv[ni] = beta [dbase + ni * 16 + lm];
    }
    float* __restrict__ ob = out + (size_t)b * 16384;
    #pragma unroll
    for (int mi = 0; mi < 4; ++mi)
    #pragma unroll
    for (int r = 0; r < 4; ++r) {
        const int row = mi * 16 + hi * 4 + r;
        const float m  = mr[row * 2 + 0];
        const float rs = mr[row * 2 + 1];
        #pragma unroll
        for (int ni = 0; ni < 4; ++ni)
            ob[row * 256 + dbase + ni * 16 + lm] =
                (acc[mi * 4 + ni][r] - m) * rs * gv[ni] + bv[ni];
    }
}

extern "C" void kernel_launch(void* const* d_in, const int* in_sizes, int n_in,
                              void* d_out, int out_size, void* d_ws, size_t ws_size,
                              hipStream_t stream) {
    const float* x     = (const float*)d_in[0];
    const float* cw    = (const float*)d_in[1];   // [1,33,256,2]
    const float* gamma = (const float*)d_in[2];
    const float* beta  = (const float*)d_in[3];
    float* outp = (float*)d_out;
    unsigned short* apack = (unsigned short*)d_ws;   // 16 KB fragment tables

    pack_A_kernel<<<16, 64, 0, stream>>>(apack);
    fft_ln_kernel<<<4096, 256, 0, stream>>>(x, cw, gamma, beta, apack, outp);
}